// Round 4
// 1665.992 us; speedup vs baseline: 1.9047x; 1.9047x over previous
//
#include <hip/hip_runtime.h>

// Problem constants
#define D     512
#define KK    8          // modules per batch
#define SS    4          // workspace slots
#define GB    4          // batches per block (main kernel)
#define BTOT  8192
#define SCALE 0.04419417382415922f   // 512^-0.5
#define LN_EPS 1e-5f
#define FSTR  516        // fp32 LDS row stride (floats): 2064B, 16B-aligned rows

// ---- module-scope device scratch (no d_ws dependence; fully rewritten every launch) ----
__device__ int   g_flag;
__device__ float g_qw[SS * D];
__device__ float g_aq[SS * D];
// B operands, transposed + 4-packed fp32: addr = (k>>2)*2048 + n*4 + (k&3)
// g_bvT: Wv_w^T  (element [k][n] = Wv_w[n][k])
// g_mrT: (Wq_r^T Wk_r)^T  ([k][n] = sum_i Wq_r[i][n]*Wk_r[i][k])
// g_moT: (Wo Wv_r)^T      ([k][n] = sum_i Wo[n][i]*Wv_r[i][k])
__device__ __align__(16) float g_bvT[D * D];
__device__ __align__(16) float g_mrT[D * D];
__device__ __align__(16) float g_moT[D * D];

#define BIDX(k, n) ((((k) >> 2) << 11) + ((n) << 2) + ((k) & 3))

__device__ __forceinline__ float wred(float v){
  #pragma unroll
  for (int m = 1; m < 64; m <<= 1) v += __shfl_xor(v, m, 64);
  return v;
}

// ---------- K0: Qw[s,e] = sum_d slots[s,d]*Wq_w[e,d]  + mask-layout flag ----------
__global__ void k0_qw_flag(const float* __restrict__ wq_w, const float* __restrict__ slots,
                           const void* __restrict__ mask){
  int tid = threadIdx.x;
  if (blockIdx.x == 0){
    __shared__ int f;
    if (tid == 0) f = 0;
    __syncthreads();
    if (tid < 256){
      const unsigned char* mb = (const unsigned char*)mask;
      int nz = mb[tid*4+1] | mb[tid*4+2] | mb[tid*4+3];
      if (nz) atomicOr(&f, 1);        // any nonzero off-word byte => u8/bool layout
    }
    __syncthreads();
    if (tid == 0) g_flag = f;
  }
  int w = tid >> 6, l = tid & 63;
  int gw = blockIdx.x * 8 + w;                  // 32 waves total
  for (int i = 0; i < 64; ++i){                 // 64 dots per wave
    int dI = gw * 64 + i;
    int s = dI >> 9, e = dI & 511;
    const float* a = slots + s * D + l * 8;
    const float* b = wq_w  + e * D + l * 8;
    float acc = 0.f;
    #pragma unroll
    for (int j = 0; j < 8; ++j) acc += a[j] * b[j];
    acc = wred(acc);
    if (l == 0) g_qw[s * D + e] = acc;
  }
}

// ---------- K1: Aq[s,d] = sum_e Qw[s,e]*Wk_w[e,d] ----------
__global__ void k1_aq(const float* __restrict__ wk_w){
  int s = blockIdx.x, d = threadIdx.x;
  float a0 = 0.f, a1 = 0.f, a2 = 0.f, a3 = 0.f;
  for (int e = 0; e < D; e += 4){
    a0 += g_qw[s * D + e + 0] * wk_w[(e + 0) * D + d];
    a1 += g_qw[s * D + e + 1] * wk_w[(e + 1) * D + d];
    a2 += g_qw[s * D + e + 2] * wk_w[(e + 2) * D + d];
    a3 += g_qw[s * D + e + 3] * wk_w[(e + 3) * D + d];
  }
  g_aq[s * D + d] = (a0 + a1) + (a2 + a3);
}

// ---------- K2: composed DxD matrices, transposed + 4-packed ----------
// mode 0: g_mrT[BIDX(k,n)] = sum_i Wq_r[i][n]*Wk_r[i][k]    (n lane-fast: coalesced P loads)
// mode 1: g_moT[BIDX(k,n)] = sum_i Wo[n][i]*Wv_r[i][k]      (k lane-fast: coalesced Q loads)
__global__ void k2_mm(const float* __restrict__ P, const float* __restrict__ Q, int mode){
  if (mode == 0){
    int n = blockIdx.x * 64 + (threadIdx.x & 63);
    int k = blockIdx.y * 4 + (threadIdx.x >> 6);
    float acc = 0.f;
    for (int i = 0; i < D; ++i) acc += P[i * D + n] * Q[i * D + k];
    g_mrT[BIDX(k, n)] = acc;
  } else {
    int k = blockIdx.x * 64 + (threadIdx.x & 63);
    int n = blockIdx.y * 4 + (threadIdx.x >> 6);
    float acc = 0.f;
    for (int i = 0; i < D; ++i) acc += P[n * D + i] * Q[i * D + k];
    g_moT[BIDX(k, n)] = acc;
  }
}

// ---------- K3T: transpose + 4-pack Wv_w -> g_bvT ----------
__global__ void k3t_pack(const float* __restrict__ wv_w){
  int o = blockIdx.x * 256 + threadIdx.x;   // 0..262143
  int k = o >> 9, n = o & 511;              // n lane-fast
  g_bvT[BIDX(k, n)] = wv_w[n * D + k];      // [k][n] = Wv_w[n][k]
}

// ---------- K4: fused main, GB=4, pure fp32, coalesced-B GEMMs ----------
// GEMM scheme (all 3): out[16][512]; wave w owns all 16 rows x 64 cols (col = w*64+lane).
// Per 4-k step: 1 coalesced float4 B-load (packed layout), 16 broadcast ds_read_b128 A-loads,
// 64 v_fma. B read exactly once per block per GEMM.
__global__ __launch_bounds__(512, 4)
void k4_main(const float* __restrict__ hidden, const void* __restrict__ maskp,
             const float* __restrict__ slots,
             const float* __restrict__ gws, const float* __restrict__ bws,
             const float* __restrict__ gout, const float* __restrict__ bout,
             float* __restrict__ out){
  __shared__ __align__(16) float mixBuf[16 * FSTR];  // h_mix -> t -> v
  __shared__ __align__(16) float wsBuf[16 * FSTR];   // ws_upd (persistent GEMM2+3)
  __shared__ float attw[128];                        // [bl][s][k]
  __shared__ float attr[128];                        // [bl][k][s]
  __shared__ float part1[128], part2[128];           // LN partials [wave][row]

  const int tid = threadIdx.x;
  const int w = tid >> 6, lane = tid & 63;
  const int col = (w << 6) + lane;                   // this thread's GEMM column
  const int b0 = blockIdx.x * GB;
  const size_t gbase = (size_t)b0 * KK * D;

  // ---- P1: write-attn softmax (waves 0..3, wave = batch), all fp32 ----
  if (w < 4){
    int flag = g_flag;
    unsigned mbits = 0;
    const int gb = b0 + w;
    if (flag){
      const unsigned char* m8 = (const unsigned char*)maskp;
      #pragma unroll
      for (int k = 0; k < KK; ++k) mbits |= (m8[gb * KK + k] ? 1u : 0u) << k;
    } else {
      const int* m32 = (const int*)maskp;
      #pragma unroll
      for (int k = 0; k < KK; ++k) mbits |= (m32[gb * KK + k] ? 1u : 0u) << k;
    }
    #pragma unroll
    for (int s = 0; s < SS; ++s){
      const float* ap = g_aq + s * D + lane * 8;
      float a0 = ap[0], a1 = ap[1], a2 = ap[2], a3 = ap[3];
      float a4 = ap[4], a5 = ap[5], a6 = ap[6], a7 = ap[7];
      float lg[KK];
      #pragma unroll
      for (int k = 0; k < KK; ++k){
        const float* hp = hidden + gbase + (size_t)(w * KK + k) * D + lane * 8;
        float4 h0 = *(const float4*)hp;
        float4 h1 = *(const float4*)(hp + 4);
        float p = a0*h0.x + a1*h0.y + a2*h0.z + a3*h0.w
                + a4*h1.x + a5*h1.y + a6*h1.z + a7*h1.w;
        p = wred(p) * SCALE;
        lg[k] = ((mbits >> k) & 1u) ? p : -3.0e38f;
      }
      float mx = -3.0e38f;
      #pragma unroll
      for (int k = 0; k < KK; ++k) mx = fmaxf(mx, lg[k]);
      float pe[KK]; float sum = 0.f;
      #pragma unroll
      for (int k = 0; k < KK; ++k){ pe[k] = (lg[k] > -1e38f) ? __expf(lg[k] - mx) : 0.f; sum += pe[k]; }
      float inv = (sum > 0.f) ? 1.f / sum : 0.f;   // all-masked -> zeros (nan_to_num)
      if (lane == 0){
        #pragma unroll
        for (int k = 0; k < KK; ++k) attw[(w * SS + s) * KK + k] = pe[k] * inv;
      }
    }
  }
  __syncthreads();                              // S1: attw ready

  // ---- P2: h_mix = attn_w @ hidden (fp32) -> mixBuf ----
  {
    #pragma unroll
    for (int i = 0; i < 2; ++i){
      int chunk = i * 512 + tid;                // 1024 chunks of 8
      int row = chunk >> 6;                     // 0..15 = bl*4+s
      int c8 = (chunk & 63) * 8;
      int bl = row >> 2, s = row & 3;
      float acc[8] = {0,0,0,0,0,0,0,0};
      #pragma unroll
      for (int k = 0; k < KK; ++k){
        float a = attw[(bl * SS + s) * KK + k];
        const float* hp = hidden + gbase + (size_t)(bl * KK + k) * D + c8;
        float4 h0 = *(const float4*)hp;
        float4 h1 = *(const float4*)(hp + 4);
        acc[0] += a*h0.x; acc[1] += a*h0.y; acc[2] += a*h0.z; acc[3] += a*h0.w;
        acc[4] += a*h1.x; acc[5] += a*h1.y; acc[6] += a*h1.z; acc[7] += a*h1.w;
      }
      float4 o0 = {acc[0], acc[1], acc[2], acc[3]};
      float4 o1 = {acc[4], acc[5], acc[6], acc[7]};
      *(float4*)(mixBuf + row * FSTR + c8) = o0;
      *(float4*)(mixBuf + row * FSTR + c8 + 4) = o1;
    }
  }
  __syncthreads();                              // S2: mix ready

  // ---- GEMM1: x = h_mix @ Wv_w^T + slots; LN -> wsBuf (ws_upd) ----
  {
    float acc[16];
    #pragma unroll
    for (int r = 0; r < 16; ++r) acc[r] = 0.f;
    const float* bp = g_bvT + (col << 2);
    #pragma unroll 2
    for (int k0 = 0; k0 < D; k0 += 4){
      float4 b = *(const float4*)(bp + (k0 << 9));     // (k0/4)*2048
      #pragma unroll
      for (int r = 0; r < 16; ++r){
        float4 a = *(const float4*)(mixBuf + r * FSTR + k0);
        acc[r] += a.x*b.x + a.y*b.y + a.z*b.z + a.w*b.w;
      }
    }
    // x = proj + slots[row&3]; per-row LN partials across 8 waves
    float x[16];
    #pragma unroll
    for (int r = 0; r < 16; ++r){
      float v = acc[r] + slots[(r & 3) * D + col];
      x[r] = v;
      float s1 = wred(v);
      float s2 = wred(v * v);
      if (lane == 0){ part1[w * 16 + r] = s1; part2[w * 16 + r] = s2; }
    }
    __syncthreads();                            // S3: partials ready; mixBuf reads done
    float gv = gws[col], bv = bws[col];
    #pragma unroll
    for (int r = 0; r < 16; ++r){
      float S1 = 0.f, S2 = 0.f;
      #pragma unroll
      for (int ww = 0; ww < 8; ++ww){ S1 += part1[ww * 16 + r]; S2 += part2[ww * 16 + r]; }
      float mu = S1 * (1.f / D);
      float rs = rsqrtf(S2 * (1.f / D) - mu * mu + LN_EPS);
      wsBuf[r * FSTR + col] = (x[r] - mu) * rs * gv + bv;
    }
  }
  __syncthreads();                              // S4: ws_upd complete

  // ---- GEMM2: t = SCALE*(ws_upd @ Mr^T) -> mixBuf ----
  {
    float acc[16];
    #pragma unroll
    for (int r = 0; r < 16; ++r) acc[r] = 0.f;
    const float* bp = g_mrT + (col << 2);
    #pragma unroll 2
    for (int k0 = 0; k0 < D; k0 += 4){
      float4 b = *(const float4*)(bp + (k0 << 9));
      #pragma unroll
      for (int r = 0; r < 16; ++r){
        float4 a = *(const float4*)(wsBuf + r * FSTR + k0);
        acc[r] += a.x*b.x + a.y*b.y + a.z*b.z + a.w*b.w;
      }
    }
    #pragma unroll
    for (int r = 0; r < 16; ++r) mixBuf[r * FSTR + col] = acc[r] * SCALE;
  }
  __syncthreads();                              // S5: t ready

  // ---- P5: read-attn softmax over s (fp32 hidden x fp32 t) ----
  {
    int bl = w >> 1, kb = (w & 1) * 4;
    #pragma unroll
    for (int kk = 0; kk < 4; ++kk){
      int k = kb + kk;
      const float* hp = hidden + gbase + (size_t)(bl * KK + k) * D + lane * 8;
      float4 h0 = *(const float4*)hp;
      float4 h1 = *(const float4*)(hp + 4);
      float hx[8] = {h0.x,h0.y,h0.z,h0.w,h1.x,h1.y,h1.z,h1.w};
      float lg[SS];
      #pragma unroll
      for (int s = 0; s < SS; ++s){
        const float* tp = mixBuf + (bl * SS + s) * FSTR + lane * 8;
        float4 t0 = *(const float4*)tp;
        float4 t1 = *(const float4*)(tp + 4);
        float p = hx[0]*t0.x + hx[1]*t0.y + hx[2]*t0.z + hx[3]*t0.w
                + hx[4]*t1.x + hx[5]*t1.y + hx[6]*t1.z + hx[7]*t1.w;
        lg[s] = wred(p);                        // t already carries SCALE
      }
      float mx = fmaxf(fmaxf(lg[0], lg[1]), fmaxf(lg[2], lg[3]));
      float pe[SS]; float sum = 0.f;
      #pragma unroll
      for (int s = 0; s < SS; ++s){ pe[s] = __expf(lg[s] - mx); sum += pe[s]; }
      float inv = 1.f / sum;
      if (lane == 0){
        #pragma unroll
        for (int s = 0; s < SS; ++s) attr[(bl * KK + k) * SS + s] = pe[s] * inv;
      }
    }
  }
  __syncthreads();                              // S6: t consumed, attr ready

  // ---- GEMM3: v = ws_upd @ Mo^T -> mixBuf ----
  {
    float acc[16];
    #pragma unroll
    for (int r = 0; r < 16; ++r) acc[r] = 0.f;
    const float* bp = g_moT + (col << 2);
    #pragma unroll 2
    for (int k0 = 0; k0 < D; k0 += 4){
      float4 b = *(const float4*)(bp + (k0 << 9));
      #pragma unroll
      for (int r = 0; r < 16; ++r){
        float4 a = *(const float4*)(wsBuf + r * FSTR + k0);
        acc[r] += a.x*b.x + a.y*b.y + a.z*b.z + a.w*b.w;
      }
    }
    // S6 already guarantees all P5 t-reads done; k-loop touched only wsBuf
    #pragma unroll
    for (int r = 0; r < 16; ++r) mixBuf[r * FSTR + col] = acc[r];
  }
  __syncthreads();                              // S7: v ready

  // ---- P6: out = LN(hidden + sum_s p_s * v_s), fp32 ----
  {
    #pragma unroll
    for (int i = 0; i < 4; ++i){
      int row = w * 4 + i;                      // flat = bl*8+k
      int bl = row >> 3;
      float p0 = attr[row * SS + 0], p1 = attr[row * SS + 1];
      float p2 = attr[row * SS + 2], p3 = attr[row * SS + 3];
      float x[8]; float s1 = 0.f, s2 = 0.f;
      #pragma unroll
      for (int j2 = 0; j2 < 2; ++j2){
        int c2 = j2 * 256 + lane * 4;
        float4 hv = *(const float4*)(hidden + gbase + (size_t)row * D + c2);
        float4 v0 = *(const float4*)(mixBuf + (bl * SS + 0) * FSTR + c2);
        float4 v1 = *(const float4*)(mixBuf + (bl * SS + 1) * FSTR + c2);
        float4 v2 = *(const float4*)(mixBuf + (bl * SS + 2) * FSTR + c2);
        float4 v3 = *(const float4*)(mixBuf + (bl * SS + 3) * FSTR + c2);
        float hx[4] = {hv.x, hv.y, hv.z, hv.w};
        float vx0[4] = {v0.x, v0.y, v0.z, v0.w};
        float vx1[4] = {v1.x, v1.y, v1.z, v1.w};
        float vx2[4] = {v2.x, v2.y, v2.z, v2.w};
        float vx3[4] = {v3.x, v3.y, v3.z, v3.w};
        #pragma unroll
        for (int j = 0; j < 4; ++j){
          float xv = hx[j] + p0*vx0[j] + p1*vx1[j] + p2*vx2[j] + p3*vx3[j];
          x[j2 * 4 + j] = xv; s1 += xv; s2 += xv * xv;
        }
      }
      s1 = wred(s1); s2 = wred(s2);
      float mu = s1 * (1.f / D);
      float rs = rsqrtf(s2 * (1.f / D) - mu * mu + LN_EPS);
      #pragma unroll
      for (int j2 = 0; j2 < 2; ++j2){
        int c2 = j2 * 256 + lane * 4;
        float4 g  = *(const float4*)(gout + c2);
        float4 bb = *(const float4*)(bout + c2);
        float4 o;
        o.x = (x[j2*4+0] - mu) * rs * g.x + bb.x;
        o.y = (x[j2*4+1] - mu) * rs * g.y + bb.y;
        o.z = (x[j2*4+2] - mu) * rs * g.z + bb.z;
        o.w = (x[j2*4+3] - mu) * rs * g.w + bb.w;
        *(float4*)(out + gbase + (size_t)row * D + c2) = o;
      }
    }
  }
}

extern "C" void kernel_launch(void* const* d_in, const int* in_sizes, int n_in,
                              void* d_out, int out_size, void* d_ws, size_t ws_size,
                              hipStream_t stream){
  const float* hidden = (const float*)d_in[0];
  const void*  mask   = d_in[1];
  const float* slots  = (const float*)d_in[2];
  const float* wq_w   = (const float*)d_in[3];
  const float* wk_w   = (const float*)d_in[4];
  const float* wv_w   = (const float*)d_in[5];
  const float* wq_r   = (const float*)d_in[6];
  const float* wk_r   = (const float*)d_in[7];
  const float* wv_r   = (const float*)d_in[8];
  const float* wo     = (const float*)d_in[9];
  const float* g_ws_  = (const float*)d_in[10];
  const float* b_ws_  = (const float*)d_in[11];
  const float* g_out_ = (const float*)d_in[12];
  const float* b_out_ = (const float*)d_in[13];

  hipLaunchKernelGGL(k0_qw_flag, dim3(4), dim3(512), 0, stream, wq_w, slots, mask);
  hipLaunchKernelGGL(k1_aq,      dim3(4), dim3(512), 0, stream, wk_w);
  hipLaunchKernelGGL(k2_mm,      dim3(8,128), dim3(256), 0, stream, wq_r, wk_r, 0);
  hipLaunchKernelGGL(k2_mm,      dim3(8,128), dim3(256), 0, stream, wo,   wv_r, 1);
  hipLaunchKernelGGL(k3t_pack,   dim3(1024), dim3(256), 0, stream, wv_w);

  hipLaunchKernelGGL(k4_main, dim3(BTOT / GB), dim3(512), 0, stream,
                     hidden, mask, slots, g_ws_, b_ws_, g_out_, b_out_, (float*)d_out);
}

// Round 5
// 1340.940 us; speedup vs baseline: 2.3664x; 1.2424x over previous
//
#include <hip/hip_runtime.h>

// Problem constants
#define D     512
#define KK    8          // modules per batch
#define SS    4          // workspace slots
#define GB    4          // batches per block (main kernel)
#define BTOT  8192
#define SCALE 0.04419417382415922f   // 512^-0.5
#define LN_EPS 1e-5f
#define FSTR  516        // fp32 LDS row stride (floats): 2064B, 16B-aligned rows

// ---- module-scope device scratch (no d_ws dependence; fully rewritten every launch) ----
__device__ int   g_flag;
__device__ float g_qw[SS * D];
__device__ float g_aq[SS * D];
// B operands, transposed + 4-packed fp32: addr = (k>>2)*2048 + n*4 + (k&3)
// g_bvT: Wv_w^T  (element [k][n] = Wv_w[n][k])
// g_mrT: (Wq_r^T Wk_r)^T  ([k][n] = sum_i Wq_r[i][n]*Wk_r[i][k])
// g_moT: (Wo Wv_r)^T      ([k][n] = sum_i Wo[n][i]*Wv_r[i][k])
__device__ __align__(16) float g_bvT[D * D];
__device__ __align__(16) float g_mrT[D * D];
__device__ __align__(16) float g_moT[D * D];

#define BIDX(k, n) ((((k) >> 2) << 11) + ((n) << 2) + ((k) & 3))

__device__ __forceinline__ float wred(float v){
  #pragma unroll
  for (int m = 1; m < 64; m <<= 1) v += __shfl_xor(v, m, 64);
  return v;
}
__device__ __forceinline__ float dot4(float4 a, float4 b, float acc){
  return fmaf(a.x, b.x, fmaf(a.y, b.y, fmaf(a.z, b.z, fmaf(a.w, b.w, acc))));
}

// ---------- K0: Qw[s,e] = sum_d slots[s,d]*Wq_w[e,d]  + mask-layout flag ----------
__global__ void k0_qw_flag(const float* __restrict__ wq_w, const float* __restrict__ slots,
                           const void* __restrict__ mask){
  int tid = threadIdx.x;
  if (blockIdx.x == 0){
    __shared__ int f;
    if (tid == 0) f = 0;
    __syncthreads();
    if (tid < 256){
      const unsigned char* mb = (const unsigned char*)mask;
      int nz = mb[tid*4+1] | mb[tid*4+2] | mb[tid*4+3];
      if (nz) atomicOr(&f, 1);        // any nonzero off-word byte => u8/bool layout
    }
    __syncthreads();
    if (tid == 0) g_flag = f;
  }
  int w = tid >> 6, l = tid & 63;
  int gw = blockIdx.x * 8 + w;                  // 32 waves total
  for (int i = 0; i < 64; ++i){                 // 64 dots per wave
    int dI = gw * 64 + i;
    int s = dI >> 9, e = dI & 511;
    const float* a = slots + s * D + l * 8;
    const float* b = wq_w  + e * D + l * 8;
    float acc = 0.f;
    #pragma unroll
    for (int j = 0; j < 8; ++j) acc = fmaf(a[j], b[j], acc);
    acc = wred(acc);
    if (l == 0) g_qw[s * D + e] = acc;
  }
}

// ---------- K1: Aq[s,d] = sum_e Qw[s,e]*Wk_w[e,d] ----------
__global__ void k1_aq(const float* __restrict__ wk_w){
  int s = blockIdx.x, d = threadIdx.x;
  float a0 = 0.f, a1 = 0.f, a2 = 0.f, a3 = 0.f;
  for (int e = 0; e < D; e += 4){
    a0 = fmaf(g_qw[s * D + e + 0], wk_w[(e + 0) * D + d], a0);
    a1 = fmaf(g_qw[s * D + e + 1], wk_w[(e + 1) * D + d], a1);
    a2 = fmaf(g_qw[s * D + e + 2], wk_w[(e + 2) * D + d], a2);
    a3 = fmaf(g_qw[s * D + e + 3], wk_w[(e + 3) * D + d], a3);
  }
  g_aq[s * D + d] = (a0 + a1) + (a2 + a3);
}

// ---------- K2: composed DxD matrices, transposed + 4-packed ----------
// mode 0: g_mrT[BIDX(k,n)] = sum_i Wq_r[i][n]*Wk_r[i][k]    (n lane-fast: coalesced P loads)
// mode 1: g_moT[BIDX(k,n)] = sum_i Wo[n][i]*Wv_r[i][k]      (k lane-fast: coalesced Q loads)
__global__ void k2_mm(const float* __restrict__ P, const float* __restrict__ Q, int mode){
  if (mode == 0){
    int n = blockIdx.x * 64 + (threadIdx.x & 63);
    int k = blockIdx.y * 4 + (threadIdx.x >> 6);
    float acc = 0.f;
    for (int i = 0; i < D; ++i) acc = fmaf(P[i * D + n], Q[i * D + k], acc);
    g_mrT[BIDX(k, n)] = acc;
  } else {
    int k = blockIdx.x * 64 + (threadIdx.x & 63);
    int n = blockIdx.y * 4 + (threadIdx.x >> 6);
    float acc = 0.f;
    for (int i = 0; i < D; ++i) acc = fmaf(P[n * D + i], Q[i * D + k], acc);
    g_moT[BIDX(k, n)] = acc;
  }
}

// ---------- K3T: transpose + 4-pack Wv_w -> g_bvT ----------
__global__ void k3t_pack(const float* __restrict__ wv_w){
  int o = blockIdx.x * 256 + threadIdx.x;   // 0..262143
  int k = o >> 9, n = o & 511;              // n lane-fast
  g_bvT[BIDX(k, n)] = wv_w[n * D + k];      // [k][n] = Wv_w[n][k]
}

// ---------- K4: fused main, GB=4, pure fp32, register-blocked GEMMs (R=4 x C=4) ----------
// Wave map: cg=w&1 (col half: cols cg*256 + q*64 + lane, q<4), rg=w>>1 (rows rg*4..+4).
// Per 4-k step: 4 broadcast ds_read_b128 (A rows) + 4 coalesced float4 B loads + 64 v_fma.
// LDS->RF traffic per FMA-lane = 1 B (vs 4 B at C=1): balanced against the 128 B/cy LDS pipe.
__global__ __launch_bounds__(512, 4)
void k4_main(const float* __restrict__ hidden, const void* __restrict__ maskp,
             const float* __restrict__ slots,
             const float* __restrict__ gws, const float* __restrict__ bws,
             const float* __restrict__ gout, const float* __restrict__ bout,
             float* __restrict__ out){
  __shared__ __align__(16) float mixBuf[16 * FSTR];  // h_mix -> t -> v
  __shared__ __align__(16) float wsBuf[16 * FSTR];   // ws_upd (persistent GEMM2+3)
  __shared__ float attw[128];                        // [bl][s][k]
  __shared__ float attr[128];                        // [bl][k][s]
  __shared__ float part1[32], part2[32];             // LN partials [wave][r]

  const int tid = threadIdx.x;
  const int w = tid >> 6, lane = tid & 63;
  const int cg = w & 1;                              // col half
  const int rg = w >> 1;                             // row group (4 rows)
  const int cb0 = (cg << 8) + lane;                  // col for q=0; q adds 64
  const int b0 = blockIdx.x * GB;
  const size_t gbase = (size_t)b0 * KK * D;

  // ---- P1: write-attn softmax (waves 0..3, wave = batch), all fp32 ----
  if (w < 4){
    int flag = g_flag;
    unsigned mbits = 0;
    const int gb = b0 + w;
    if (flag){
      const unsigned char* m8 = (const unsigned char*)maskp;
      #pragma unroll
      for (int k = 0; k < KK; ++k) mbits |= (m8[gb * KK + k] ? 1u : 0u) << k;
    } else {
      const int* m32 = (const int*)maskp;
      #pragma unroll
      for (int k = 0; k < KK; ++k) mbits |= (m32[gb * KK + k] ? 1u : 0u) << k;
    }
    #pragma unroll
    for (int s = 0; s < SS; ++s){
      const float* ap = g_aq + s * D + lane * 8;
      float a0 = ap[0], a1 = ap[1], a2 = ap[2], a3 = ap[3];
      float a4 = ap[4], a5 = ap[5], a6 = ap[6], a7 = ap[7];
      float lg[KK];
      #pragma unroll
      for (int k = 0; k < KK; ++k){
        const float* hp = hidden + gbase + (size_t)(w * KK + k) * D + lane * 8;
        float4 h0 = *(const float4*)hp;
        float4 h1 = *(const float4*)(hp + 4);
        float p = fmaf(a0,h0.x, fmaf(a1,h0.y, fmaf(a2,h0.z, fmaf(a3,h0.w,
                  fmaf(a4,h1.x, fmaf(a5,h1.y, fmaf(a6,h1.z, a7*h1.w)))))));
        p = wred(p) * SCALE;
        lg[k] = ((mbits >> k) & 1u) ? p : -3.0e38f;
      }
      float mx = -3.0e38f;
      #pragma unroll
      for (int k = 0; k < KK; ++k) mx = fmaxf(mx, lg[k]);
      float pe[KK]; float sum = 0.f;
      #pragma unroll
      for (int k = 0; k < KK; ++k){ pe[k] = (lg[k] > -1e38f) ? __expf(lg[k] - mx) : 0.f; sum += pe[k]; }
      float inv = (sum > 0.f) ? 1.f / sum : 0.f;   // all-masked -> zeros (nan_to_num)
      if (lane == 0){
        #pragma unroll
        for (int k = 0; k < KK; ++k) attw[(w * SS + s) * KK + k] = pe[k] * inv;
      }
    }
  }
  __syncthreads();                              // S1: attw ready

  // ---- P2: h_mix = attn_w @ hidden (fp32) -> mixBuf ----
  {
    #pragma unroll
    for (int i = 0; i < 2; ++i){
      int chunk = i * 512 + tid;                // 1024 chunks of 8
      int row = chunk >> 6;                     // 0..15 = bl*4+s
      int c8 = (chunk & 63) * 8;
      int bl = row >> 2, s = row & 3;
      float acc[8] = {0,0,0,0,0,0,0,0};
      #pragma unroll
      for (int k = 0; k < KK; ++k){
        float a = attw[(bl * SS + s) * KK + k];
        const float* hp = hidden + gbase + (size_t)(bl * KK + k) * D + c8;
        float4 h0 = *(const float4*)hp;
        float4 h1 = *(const float4*)(hp + 4);
        acc[0] = fmaf(a,h0.x,acc[0]); acc[1] = fmaf(a,h0.y,acc[1]);
        acc[2] = fmaf(a,h0.z,acc[2]); acc[3] = fmaf(a,h0.w,acc[3]);
        acc[4] = fmaf(a,h1.x,acc[4]); acc[5] = fmaf(a,h1.y,acc[5]);
        acc[6] = fmaf(a,h1.z,acc[6]); acc[7] = fmaf(a,h1.w,acc[7]);
      }
      float4 o0 = {acc[0], acc[1], acc[2], acc[3]};
      float4 o1 = {acc[4], acc[5], acc[6], acc[7]};
      *(float4*)(mixBuf + row * FSTR + c8) = o0;
      *(float4*)(mixBuf + row * FSTR + c8 + 4) = o1;
    }
  }
  __syncthreads();                              // S2: mix ready

  // ---- GEMM1: x = h_mix @ Wv_w^T + slots; LN -> wsBuf (ws_upd) ----
  {
    float acc[4][4];                            // [r][q]
    #pragma unroll
    for (int r = 0; r < 4; ++r)
      #pragma unroll
      for (int q = 0; q < 4; ++q) acc[r][q] = 0.f;
    const float* bp = g_bvT + (cb0 << 2);
    const float* ap = mixBuf + (rg << 2) * FSTR;
    #pragma unroll 2
    for (int k0 = 0; k0 < D; k0 += 4){
      const float* bk = bp + (k0 << 9);
      float4 b0 = *(const float4*)(bk);
      float4 b1 = *(const float4*)(bk + 256);
      float4 b2 = *(const float4*)(bk + 512);
      float4 b3 = *(const float4*)(bk + 768);
      #pragma unroll
      for (int r = 0; r < 4; ++r){
        float4 a = *(const float4*)(ap + r * FSTR + k0);
        acc[r][0] = dot4(a, b0, acc[r][0]);
        acc[r][1] = dot4(a, b1, acc[r][1]);
        acc[r][2] = dot4(a, b2, acc[r][2]);
        acc[r][3] = dot4(a, b3, acc[r][3]);
      }
    }
    // x = proj + slots[row&3]; per-row LN partials (2 waves per row-quad)
    float x[4][4];
    #pragma unroll
    for (int r = 0; r < 4; ++r){
      int row = (rg << 2) + r;
      float s1 = 0.f, s2 = 0.f;
      #pragma unroll
      for (int q = 0; q < 4; ++q){
        float v = acc[r][q] + slots[(row & 3) * D + cb0 + (q << 6)];
        x[r][q] = v; s1 += v; s2 = fmaf(v, v, s2);
      }
      s1 = wred(s1); s2 = wred(s2);
      if (lane == 0){ part1[w * 4 + r] = s1; part2[w * 4 + r] = s2; }
    }
    __syncthreads();                            // S3: partials ready; mixBuf reads done
    float gv[4], bv[4];
    #pragma unroll
    for (int q = 0; q < 4; ++q){ gv[q] = gws[cb0 + (q << 6)]; bv[q] = bws[cb0 + (q << 6)]; }
    #pragma unroll
    for (int r = 0; r < 4; ++r){
      int row = (rg << 2) + r;
      float S1 = part1[(rg << 3) + r] + part1[(rg << 3) + 4 + r];
      float S2 = part2[(rg << 3) + r] + part2[(rg << 3) + 4 + r];
      float mu = S1 * (1.f / D);
      float rs = rsqrtf(S2 * (1.f / D) - mu * mu + LN_EPS);
      #pragma unroll
      for (int q = 0; q < 4; ++q)
        wsBuf[row * FSTR + cb0 + (q << 6)] = (x[r][q] - mu) * rs * gv[q] + bv[q];
    }
  }
  __syncthreads();                              // S4: ws_upd complete

  // ---- GEMM2: t = SCALE*(ws_upd @ Mr^T) -> mixBuf ----
  {
    float acc[4][4];
    #pragma unroll
    for (int r = 0; r < 4; ++r)
      #pragma unroll
      for (int q = 0; q < 4; ++q) acc[r][q] = 0.f;
    const float* bp = g_mrT + (cb0 << 2);
    const float* ap = wsBuf + (rg << 2) * FSTR;
    #pragma unroll 2
    for (int k0 = 0; k0 < D; k0 += 4){
      const float* bk = bp + (k0 << 9);
      float4 b0 = *(const float4*)(bk);
      float4 b1 = *(const float4*)(bk + 256);
      float4 b2 = *(const float4*)(bk + 512);
      float4 b3 = *(const float4*)(bk + 768);
      #pragma unroll
      for (int r = 0; r < 4; ++r){
        float4 a = *(const float4*)(ap + r * FSTR + k0);
        acc[r][0] = dot4(a, b0, acc[r][0]);
        acc[r][1] = dot4(a, b1, acc[r][1]);
        acc[r][2] = dot4(a, b2, acc[r][2]);
        acc[r][3] = dot4(a, b3, acc[r][3]);
      }
    }
    #pragma unroll
    for (int r = 0; r < 4; ++r){
      int row = (rg << 2) + r;
      #pragma unroll
      for (int q = 0; q < 4; ++q)
        mixBuf[row * FSTR + cb0 + (q << 6)] = acc[r][q] * SCALE;
    }
  }
  __syncthreads();                              // S5: t ready

  // ---- P5: read-attn softmax over s (fp32 hidden x fp32 t) ----
  {
    int bl = w >> 1, kb = (w & 1) * 4;
    #pragma unroll
    for (int kk = 0; kk < 4; ++kk){
      int k = kb + kk;
      const float* hp = hidden + gbase + (size_t)(bl * KK + k) * D + lane * 8;
      float4 h0 = *(const float4*)hp;
      float4 h1 = *(const float4*)(hp + 4);
      float lg[SS];
      #pragma unroll
      for (int s = 0; s < SS; ++s){
        const float* tp = mixBuf + (bl * SS + s) * FSTR + lane * 8;
        float4 t0 = *(const float4*)tp;
        float4 t1 = *(const float4*)(tp + 4);
        float p = dot4(h1, t1, dot4(h0, t0, 0.f));
        lg[s] = wred(p);                        // t already carries SCALE
      }
      float mx = fmaxf(fmaxf(lg[0], lg[1]), fmaxf(lg[2], lg[3]));
      float pe[SS]; float sum = 0.f;
      #pragma unroll
      for (int s = 0; s < SS; ++s){ pe[s] = __expf(lg[s] - mx); sum += pe[s]; }
      float inv = 1.f / sum;
      if (lane == 0){
        #pragma unroll
        for (int s = 0; s < SS; ++s) attr[(bl * KK + k) * SS + s] = pe[s] * inv;
      }
    }
  }
  __syncthreads();                              // S6: t consumed, attr ready

  // ---- GEMM3: v = ws_upd @ Mo^T -> mixBuf ----
  {
    float acc[4][4];
    #pragma unroll
    for (int r = 0; r < 4; ++r)
      #pragma unroll
      for (int q = 0; q < 4; ++q) acc[r][q] = 0.f;
    const float* bp = g_moT + (cb0 << 2);
    const float* ap = wsBuf + (rg << 2) * FSTR;
    #pragma unroll 2
    for (int k0 = 0; k0 < D; k0 += 4){
      const float* bk = bp + (k0 << 9);
      float4 b0 = *(const float4*)(bk);
      float4 b1 = *(const float4*)(bk + 256);
      float4 b2 = *(const float4*)(bk + 512);
      float4 b3 = *(const float4*)(bk + 768);
      #pragma unroll
      for (int r = 0; r < 4; ++r){
        float4 a = *(const float4*)(ap + r * FSTR + k0);
        acc[r][0] = dot4(a, b0, acc[r][0]);
        acc[r][1] = dot4(a, b1, acc[r][1]);
        acc[r][2] = dot4(a, b2, acc[r][2]);
        acc[r][3] = dot4(a, b3, acc[r][3]);
      }
    }
    // S6 already fenced all P5 t-reads; k-loop touched only wsBuf
    #pragma unroll
    for (int r = 0; r < 4; ++r){
      int row = (rg << 2) + r;
      #pragma unroll
      for (int q = 0; q < 4; ++q)
        mixBuf[row * FSTR + cb0 + (q << 6)] = acc[r][q];
    }
  }
  __syncthreads();                              // S7: v ready

  // ---- P6: out = LN(hidden + sum_s p_s * v_s), fp32 ----
  {
    #pragma unroll
    for (int i = 0; i < 4; ++i){
      int row = w * 4 + i;                      // flat = bl*8+k
      int bl = row >> 3;
      float p0 = attr[row * SS + 0], p1 = attr[row * SS + 1];
      float p2 = attr[row * SS + 2], p3 = attr[row * SS + 3];
      float x[8]; float s1 = 0.f, s2 = 0.f;
      #pragma unroll
      for (int j2 = 0; j2 < 2; ++j2){
        int c2 = j2 * 256 + lane * 4;
        float4 hv = *(const float4*)(hidden + gbase + (size_t)row * D + c2);
        float4 v0 = *(const float4*)(mixBuf + (bl * SS + 0) * FSTR + c2);
        float4 v1 = *(const float4*)(mixBuf + (bl * SS + 1) * FSTR + c2);
        float4 v2 = *(const float4*)(mixBuf + (bl * SS + 2) * FSTR + c2);
        float4 v3 = *(const float4*)(mixBuf + (bl * SS + 3) * FSTR + c2);
        float hx[4] = {hv.x, hv.y, hv.z, hv.w};
        float vx0[4] = {v0.x, v0.y, v0.z, v0.w};
        float vx1[4] = {v1.x, v1.y, v1.z, v1.w};
        float vx2[4] = {v2.x, v2.y, v2.z, v2.w};
        float vx3[4] = {v3.x, v3.y, v3.z, v3.w};
        #pragma unroll
        for (int j = 0; j < 4; ++j){
          float xv = hx[j];
          xv = fmaf(p0, vx0[j], xv);
          xv = fmaf(p1, vx1[j], xv);
          xv = fmaf(p2, vx2[j], xv);
          xv = fmaf(p3, vx3[j], xv);
          x[j2 * 4 + j] = xv; s1 += xv; s2 = fmaf(xv, xv, s2);
        }
      }
      s1 = wred(s1); s2 = wred(s2);
      float mu = s1 * (1.f / D);
      float rs = rsqrtf(s2 * (1.f / D) - mu * mu + LN_EPS);
      #pragma unroll
      for (int j2 = 0; j2 < 2; ++j2){
        int c2 = j2 * 256 + lane * 4;
        float4 g  = *(const float4*)(gout + c2);
        float4 bb = *(const float4*)(bout + c2);
        float4 o;
        o.x = (x[j2*4+0] - mu) * rs * g.x + bb.x;
        o.y = (x[j2*4+1] - mu) * rs * g.y + bb.y;
        o.z = (x[j2*4+2] - mu) * rs * g.z + bb.z;
        o.w = (x[j2*4+3] - mu) * rs * g.w + bb.w;
        *(float4*)(out + gbase + (size_t)row * D + c2) = o;
      }
    }
  }
}

extern "C" void kernel_launch(void* const* d_in, const int* in_sizes, int n_in,
                              void* d_out, int out_size, void* d_ws, size_t ws_size,
                              hipStream_t stream){
  const float* hidden = (const float*)d_in[0];
  const void*  mask   = d_in[1];
  const float* slots  = (const float*)d_in[2];
  const float* wq_w   = (const float*)d_in[3];
  const float* wk_w   = (const float*)d_in[4];
  const float* wv_w   = (const float*)d_in[5];
  const float* wq_r   = (const float*)d_in[6];
  const float* wk_r   = (const float*)d_in[7];
  const float* wv_r   = (const float*)d_in[8];
  const float* wo     = (const float*)d_in[9];
  const float* g_ws_  = (const float*)d_in[10];
  const float* b_ws_  = (const float*)d_in[11];
  const float* g_out_ = (const float*)d_in[12];
  const float* b_out_ = (const float*)d_in[13];

  hipLaunchKernelGGL(k0_qw_flag, dim3(4), dim3(512), 0, stream, wq_w, slots, mask);
  hipLaunchKernelGGL(k1_aq,      dim3(4), dim3(512), 0, stream, wk_w);
  hipLaunchKernelGGL(k2_mm,      dim3(8,128), dim3(256), 0, stream, wq_r, wk_r, 0);
  hipLaunchKernelGGL(k2_mm,      dim3(8,128), dim3(256), 0, stream, wo,   wv_r, 1);
  hipLaunchKernelGGL(k3t_pack,   dim3(1024), dim3(256), 0, stream, wv_w);

  hipLaunchKernelGGL(k4_main, dim3(BTOT / GB), dim3(512), 0, stream,
                     hidden, mask, slots, g_ws_, b_ws_, g_out_, b_out_, (float*)d_out);
}

// Round 6
// 1083.651 us; speedup vs baseline: 2.9282x; 1.2374x over previous
//
#include <hip/hip_runtime.h>

// Problem constants
#define D     512
#define KK    8          // modules per batch
#define SS    4          // workspace slots
#define GB    4          // batches per block (main kernel)
#define BTOT  8192
#define SCALE 0.04419417382415922f   // 512^-0.5
#define LN_EPS 1e-5f
#define FSTR  516        // fp32 LDS row stride (floats): 2064B, 16B-aligned rows

// ---- module-scope device scratch (fully rewritten every launch) ----
__device__ int   g_flag;
__device__ float g_aq[SS * D];
__device__ __align__(16) float g_mw[D * D];    // Wq_w^T Wk_w, plain row-major [d][d']
// B operands, transposed + 4-packed fp32: addr = (k>>2)*2048 + n*4 + (k&3)
__device__ __align__(16) float g_bvT[D * D];   // [k][n] = Wv_w[n][k]
__device__ __align__(16) float g_mrT[D * D];   // [k][n] = Mr[n][k] = sum_i Wq_r[i][n]*Wk_r[i][k]
__device__ __align__(16) float g_moT[D * D];   // [k][n] = Mo[n][k] = sum_i Wo[n][i]*Wv_r[i][k]

#define BIDX(k, n) ((((k) >> 2) << 11) + ((n) << 2) + ((k) & 3))

__device__ __forceinline__ float wred(float v){
  #pragma unroll
  for (int m = 1; m < 64; m <<= 1) v += __shfl_xor(v, m, 64);
  return v;
}
__device__ __forceinline__ float dot4(float4 a, float4 b, float acc){
  return fmaf(a.x, b.x, fmaf(a.y, b.y, fmaf(a.z, b.z, fmaf(a.w, b.w, acc))));
}

// ---------- KPREP: all weight-composition products in one launch ----------
// z=0: g_mw[d][d']   = sum_e Wq_w[e,d]*Wk_w[e,d']   (plain row-major)
// z=1: g_mrT[BIDX]   = sum_i Wq_r[i,n]*Wk_r[i,k]    (packed, n lane-fast)
// z=2: g_moT[BIDX]   = sum_i Wo[n,i]*Wv_r[i,k]      (packed, k lane-fast)
// z=3: g_bvT[BIDX]   = Wv_w[n][k]                   (transpose pack)
// grid (8,32,4) x 256 threads; 4 outputs/thread via 4-wide register blocking.
__global__ void kprep(const float* __restrict__ wq_w, const float* __restrict__ wk_w,
                      const float* __restrict__ wq_r, const float* __restrict__ wk_r,
                      const float* __restrict__ wo,   const float* __restrict__ wv_r,
                      const float* __restrict__ wv_w){
  const int tid = threadIdx.x, w = tid >> 6, lane = tid & 63;
  const int bx = blockIdx.x, by = blockIdx.y, z = blockIdx.z;
  if (z == 3){                                   // transpose pack Wv_w
    int o0 = (by * 8 + bx) * 256 + tid;          // 0..65535
    #pragma unroll
    for (int j = 0; j < 4; ++j){
      int idx = o0 + j * 65536;                  // k lane-fast: coalesced reads
      int k = idx & 511, n = idx >> 9;
      g_bvT[BIDX(k, n)] = wv_w[n * D + k];
    }
    return;
  }
  float acc[4] = {0.f, 0.f, 0.f, 0.f};
  if (z == 0){
    int dp = bx * 64 + lane;                     // coalesced over Wk_w
    int d0 = by * 16 + w * 4;                    // 4 consecutive d per thread
    for (int e = 0; e < D; ++e){
      float4 p = *(const float4*)(wq_w + e * D + d0);   // broadcast float4
      float  q = wk_w[e * D + dp];
      acc[0] = fmaf(p.x, q, acc[0]); acc[1] = fmaf(p.y, q, acc[1]);
      acc[2] = fmaf(p.z, q, acc[2]); acc[3] = fmaf(p.w, q, acc[3]);
    }
    #pragma unroll
    for (int j = 0; j < 4; ++j) g_mw[(d0 + j) * D + dp] = acc[j];
  } else if (z == 1){
    int n = bx * 64 + lane;                      // coalesced over Wq_r
    int k0 = by * 16 + w * 4;
    for (int i = 0; i < D; ++i){
      float4 q = *(const float4*)(wk_r + i * D + k0);   // broadcast float4
      float  p = wq_r[i * D + n];
      acc[0] = fmaf(p, q.x, acc[0]); acc[1] = fmaf(p, q.y, acc[1]);
      acc[2] = fmaf(p, q.z, acc[2]); acc[3] = fmaf(p, q.w, acc[3]);
    }
    #pragma unroll
    for (int j = 0; j < 4; ++j) g_mrT[BIDX(k0 + j, n)] = acc[j];
  } else {
    int k = bx * 64 + lane;                      // coalesced over Wv_r
    int n0 = by * 16 + w * 4;
    for (int i = 0; i < D; ++i){
      float q = wv_r[i * D + k];
      acc[0] = fmaf(wo[(n0 + 0) * D + i], q, acc[0]);
      acc[1] = fmaf(wo[(n0 + 1) * D + i], q, acc[1]);
      acc[2] = fmaf(wo[(n0 + 2) * D + i], q, acc[2]);
      acc[3] = fmaf(wo[(n0 + 3) * D + i], q, acc[3]);
    }
    #pragma unroll
    for (int j = 0; j < 4; ++j) g_moT[BIDX(k, n0 + j)] = acc[j];
  }
}

// ---------- KAQ: g_aq[s] = slots[s] @ g_mw  + mask-layout flag ----------
__global__ void kaq(const float* __restrict__ slots, const void* __restrict__ mask){
  int s = blockIdx.x, d = threadIdx.x;
  if (blockIdx.x == 0){
    __shared__ int f;
    if (d == 0) f = 0;
    __syncthreads();
    if (d < 256){
      const unsigned char* mb = (const unsigned char*)mask;
      int nz = mb[d*4+1] | mb[d*4+2] | mb[d*4+3];
      if (nz) atomicOr(&f, 1);        // any nonzero off-word byte => u8/bool layout
    }
    __syncthreads();
    if (d == 0) g_flag = f;
  }
  float a0 = 0.f, a1 = 0.f, a2 = 0.f, a3 = 0.f;
  for (int e = 0; e < D; e += 4){
    a0 = fmaf(slots[s * D + e + 0], g_mw[(e + 0) * D + d], a0);
    a1 = fmaf(slots[s * D + e + 1], g_mw[(e + 1) * D + d], a1);
    a2 = fmaf(slots[s * D + e + 2], g_mw[(e + 2) * D + d], a2);
    a3 = fmaf(slots[s * D + e + 3], g_mw[(e + 3) * D + d], a3);
  }
  g_aq[s * D + d] = (a0 + a1) + (a2 + a3);
}

// ---------- K4: fused main, GB=4, pure fp32, register-blocked GEMMs (R=8 x C=2) ----------
// Wave map: cg=w&3 (128-col group: cols cg*128 + q*64 + lane, q<2), rg=w>>2 (rows rg*8..+8).
// Per 4-k step: 8 broadcast ds_read_b128 (A rows, ~96cy issue < 128cy FMA) + 2 coalesced
// float4 B loads (2KB/wave/step -> ~61 B/cy/CU L1 demand, within capacity) + 64 FMA.
__global__ __launch_bounds__(512, 4)
void k4_main(const float* __restrict__ hidden, const void* __restrict__ maskp,
             const float* __restrict__ slots,
             const float* __restrict__ gws, const float* __restrict__ bws,
             const float* __restrict__ gout, const float* __restrict__ bout,
             float* __restrict__ out){
  __shared__ __align__(16) float mixBuf[16 * FSTR];  // h_mix -> t -> v
  __shared__ __align__(16) float wsBuf[16 * FSTR];   // ws_upd (persistent GEMM2+3)
  __shared__ float attw[128];                        // [bl][s][k]
  __shared__ float attr[128];                        // [bl][k][s]
  __shared__ float part1[64], part2[64];             // LN partials [cg][row]

  const int tid = threadIdx.x;
  const int w = tid >> 6, lane = tid & 63;
  const int cg = w & 3;                              // col group (128 cols)
  const int rg = w >> 2;                             // row group (8 rows)
  const int col0 = (cg << 7) + lane;                 // q=0 col; q adds 64
  const int b0 = blockIdx.x * GB;
  const size_t gbase = (size_t)b0 * KK * D;

  // ---- P1: write-attn softmax (waves 0..3, wave = batch), all fp32 ----
  if (w < 4){
    int flag = g_flag;
    unsigned mbits = 0;
    const int gb = b0 + w;
    if (flag){
      const unsigned char* m8 = (const unsigned char*)maskp;
      #pragma unroll
      for (int k = 0; k < KK; ++k) mbits |= (m8[gb * KK + k] ? 1u : 0u) << k;
    } else {
      const int* m32 = (const int*)maskp;
      #pragma unroll
      for (int k = 0; k < KK; ++k) mbits |= (m32[gb * KK + k] ? 1u : 0u) << k;
    }
    #pragma unroll
    for (int s = 0; s < SS; ++s){
      const float* ap = g_aq + s * D + lane * 8;
      float a0 = ap[0], a1 = ap[1], a2 = ap[2], a3 = ap[3];
      float a4 = ap[4], a5 = ap[5], a6 = ap[6], a7 = ap[7];
      float lg[KK];
      #pragma unroll
      for (int k = 0; k < KK; ++k){
        const float* hp = hidden + gbase + (size_t)(w * KK + k) * D + lane * 8;
        float4 h0 = *(const float4*)hp;
        float4 h1 = *(const float4*)(hp + 4);
        float p = fmaf(a0,h0.x, fmaf(a1,h0.y, fmaf(a2,h0.z, fmaf(a3,h0.w,
                  fmaf(a4,h1.x, fmaf(a5,h1.y, fmaf(a6,h1.z, a7*h1.w)))))));
        p = wred(p) * SCALE;
        lg[k] = ((mbits >> k) & 1u) ? p : -3.0e38f;
      }
      float mx = -3.0e38f;
      #pragma unroll
      for (int k = 0; k < KK; ++k) mx = fmaxf(mx, lg[k]);
      float pe[KK]; float sum = 0.f;
      #pragma unroll
      for (int k = 0; k < KK; ++k){ pe[k] = (lg[k] > -1e38f) ? __expf(lg[k] - mx) : 0.f; sum += pe[k]; }
      float inv = (sum > 0.f) ? 1.f / sum : 0.f;   // all-masked -> zeros (nan_to_num)
      if (lane == 0){
        #pragma unroll
        for (int k = 0; k < KK; ++k) attw[(w * SS + s) * KK + k] = pe[k] * inv;
      }
    }
  }
  __syncthreads();                              // S1: attw ready

  // ---- P2: h_mix = attn_w @ hidden (fp32) -> mixBuf ----
  {
    #pragma unroll
    for (int i = 0; i < 2; ++i){
      int chunk = i * 512 + tid;                // 1024 chunks of 8
      int row = chunk >> 6;                     // 0..15 = bl*4+s
      int c8 = (chunk & 63) * 8;
      int bl = row >> 2, s = row & 3;
      float acc[8] = {0,0,0,0,0,0,0,0};
      #pragma unroll
      for (int k = 0; k < KK; ++k){
        float a = attw[(bl * SS + s) * KK + k];
        const float* hp = hidden + gbase + (size_t)(bl * KK + k) * D + c8;
        float4 h0 = *(const float4*)hp;
        float4 h1 = *(const float4*)(hp + 4);
        acc[0] = fmaf(a,h0.x,acc[0]); acc[1] = fmaf(a,h0.y,acc[1]);
        acc[2] = fmaf(a,h0.z,acc[2]); acc[3] = fmaf(a,h0.w,acc[3]);
        acc[4] = fmaf(a,h1.x,acc[4]); acc[5] = fmaf(a,h1.y,acc[5]);
        acc[6] = fmaf(a,h1.z,acc[6]); acc[7] = fmaf(a,h1.w,acc[7]);
      }
      float4 o0 = {acc[0], acc[1], acc[2], acc[3]};
      float4 o1 = {acc[4], acc[5], acc[6], acc[7]};
      *(float4*)(mixBuf + row * FSTR + c8) = o0;
      *(float4*)(mixBuf + row * FSTR + c8 + 4) = o1;
    }
  }
  __syncthreads();                              // S2: mix ready

  // ---- GEMM1: x = h_mix @ Wv_w^T + slots; LN -> wsBuf (ws_upd) ----
  {
    float acc[8][2];
    #pragma unroll
    for (int r = 0; r < 8; ++r){ acc[r][0] = 0.f; acc[r][1] = 0.f; }
    const float* bp = g_bvT + (col0 << 2);
    const float* ap = mixBuf + (rg << 3) * FSTR;
    #pragma unroll 2
    for (int k0 = 0; k0 < D; k0 += 4){
      const float* bk = bp + (k0 << 9);
      float4 bq0 = *(const float4*)(bk);
      float4 bq1 = *(const float4*)(bk + 256);
      #pragma unroll
      for (int r = 0; r < 8; ++r){
        float4 a = *(const float4*)(ap + r * FSTR + k0);
        acc[r][0] = dot4(a, bq0, acc[r][0]);
        acc[r][1] = dot4(a, bq1, acc[r][1]);
      }
    }
    // x = proj + slots[row&3]; per-row LN partials across 4 col-groups
    float x[8][2];
    #pragma unroll
    for (int r = 0; r < 8; ++r){
      int row = (rg << 3) + r;
      float v0 = acc[r][0] + slots[(row & 3) * D + col0];
      float v1 = acc[r][1] + slots[(row & 3) * D + col0 + 64];
      x[r][0] = v0; x[r][1] = v1;
      float s1 = wred(v0 + v1);
      float s2 = wred(fmaf(v0, v0, v1 * v1));
      if (lane == 0){ part1[(cg << 4) + row] = s1; part2[(cg << 4) + row] = s2; }
    }
    __syncthreads();                            // S3: partials ready; mixBuf reads done
    float gv0 = gws[col0], gv1 = gws[col0 + 64];
    float bv0 = bws[col0], bv1 = bws[col0 + 64];
    #pragma unroll
    for (int r = 0; r < 8; ++r){
      int row = (rg << 3) + r;
      float S1 = (part1[row] + part1[16 + row]) + (part1[32 + row] + part1[48 + row]);
      float S2 = (part2[row] + part2[16 + row]) + (part2[32 + row] + part2[48 + row]);
      float mu = S1 * (1.f / D);
      float rs = rsqrtf(S2 * (1.f / D) - mu * mu + LN_EPS);
      wsBuf[row * FSTR + col0]      = (x[r][0] - mu) * rs * gv0 + bv0;
      wsBuf[row * FSTR + col0 + 64] = (x[r][1] - mu) * rs * gv1 + bv1;
    }
  }
  __syncthreads();                              // S4: ws_upd complete

  // ---- GEMM2: t = SCALE*(ws_upd @ Mr^T) -> mixBuf ----
  {
    float acc[8][2];
    #pragma unroll
    for (int r = 0; r < 8; ++r){ acc[r][0] = 0.f; acc[r][1] = 0.f; }
    const float* bp = g_mrT + (col0 << 2);
    const float* ap = wsBuf + (rg << 3) * FSTR;
    #pragma unroll 2
    for (int k0 = 0; k0 < D; k0 += 4){
      const float* bk = bp + (k0 << 9);
      float4 bq0 = *(const float4*)(bk);
      float4 bq1 = *(const float4*)(bk + 256);
      #pragma unroll
      for (int r = 0; r < 8; ++r){
        float4 a = *(const float4*)(ap + r * FSTR + k0);
        acc[r][0] = dot4(a, bq0, acc[r][0]);
        acc[r][1] = dot4(a, bq1, acc[r][1]);
      }
    }
    #pragma unroll
    for (int r = 0; r < 8; ++r){
      int row = (rg << 3) + r;
      mixBuf[row * FSTR + col0]      = acc[r][0] * SCALE;
      mixBuf[row * FSTR + col0 + 64] = acc[r][1] * SCALE;
    }
  }
  __syncthreads();                              // S5: t ready

  // ---- P5: read-attn softmax over s (fp32 hidden x fp32 t) ----
  {
    int bl = w >> 1, kb = (w & 1) * 4;
    #pragma unroll
    for (int kk = 0; kk < 4; ++kk){
      int k = kb + kk;
      const float* hp = hidden + gbase + (size_t)(bl * KK + k) * D + lane * 8;
      float4 h0 = *(const float4*)hp;
      float4 h1 = *(const float4*)(hp + 4);
      float lg[SS];
      #pragma unroll
      for (int s = 0; s < SS; ++s){
        const float* tp = mixBuf + (bl * SS + s) * FSTR + lane * 8;
        float4 t0 = *(const float4*)tp;
        float4 t1 = *(const float4*)(tp + 4);
        float p = dot4(h1, t1, dot4(h0, t0, 0.f));
        lg[s] = wred(p);                        // t already carries SCALE
      }
      float mx = fmaxf(fmaxf(lg[0], lg[1]), fmaxf(lg[2], lg[3]));
      float pe[SS]; float sum = 0.f;
      #pragma unroll
      for (int s = 0; s < SS; ++s){ pe[s] = __expf(lg[s] - mx); sum += pe[s]; }
      float inv = 1.f / sum;
      if (lane == 0){
        #pragma unroll
        for (int s = 0; s < SS; ++s) attr[(bl * KK + k) * SS + s] = pe[s] * inv;
      }
    }
  }
  __syncthreads();                              // S6: t consumed, attr ready

  // ---- GEMM3: v = ws_upd @ Mo^T -> mixBuf ----
  {
    float acc[8][2];
    #pragma unroll
    for (int r = 0; r < 8; ++r){ acc[r][0] = 0.f; acc[r][1] = 0.f; }
    const float* bp = g_moT + (col0 << 2);
    const float* ap = wsBuf + (rg << 3) * FSTR;
    #pragma unroll 2
    for (int k0 = 0; k0 < D; k0 += 4){
      const float* bk = bp + (k0 << 9);
      float4 bq0 = *(const float4*)(bk);
      float4 bq1 = *(const float4*)(bk + 256);
      #pragma unroll
      for (int r = 0; r < 8; ++r){
        float4 a = *(const float4*)(ap + r * FSTR + k0);
        acc[r][0] = dot4(a, bq0, acc[r][0]);
        acc[r][1] = dot4(a, bq1, acc[r][1]);
      }
    }
    // S6 already fenced all P5 t-reads; k-loop touched only wsBuf
    #pragma unroll
    for (int r = 0; r < 8; ++r){
      int row = (rg << 3) + r;
      mixBuf[row * FSTR + col0]      = acc[r][0];
      mixBuf[row * FSTR + col0 + 64] = acc[r][1];
    }
  }
  __syncthreads();                              // S7: v ready

  // ---- P6: out = LN(hidden + sum_s p_s * v_s), fp32 ----
  {
    #pragma unroll
    for (int i = 0; i < 4; ++i){
      int row = w * 4 + i;                      // flat = bl*8+k
      int bl = row >> 3;
      float p0 = attr[row * SS + 0], p1 = attr[row * SS + 1];
      float p2 = attr[row * SS + 2], p3 = attr[row * SS + 3];
      float x[8]; float s1 = 0.f, s2 = 0.f;
      #pragma unroll
      for (int j2 = 0; j2 < 2; ++j2){
        int c2 = j2 * 256 + lane * 4;
        float4 hv = *(const float4*)(hidden + gbase + (size_t)row * D + c2);
        float4 v0 = *(const float4*)(mixBuf + (bl * SS + 0) * FSTR + c2);
        float4 v1 = *(const float4*)(mixBuf + (bl * SS + 1) * FSTR + c2);
        float4 v2 = *(const float4*)(mixBuf + (bl * SS + 2) * FSTR + c2);
        float4 v3 = *(const float4*)(mixBuf + (bl * SS + 3) * FSTR + c2);
        float hx[4] = {hv.x, hv.y, hv.z, hv.w};
        float vx0[4] = {v0.x, v0.y, v0.z, v0.w};
        float vx1[4] = {v1.x, v1.y, v1.z, v1.w};
        float vx2[4] = {v2.x, v2.y, v2.z, v2.w};
        float vx3[4] = {v3.x, v3.y, v3.z, v3.w};
        #pragma unroll
        for (int j = 0; j < 4; ++j){
          float xv = hx[j];
          xv = fmaf(p0, vx0[j], xv);
          xv = fmaf(p1, vx1[j], xv);
          xv = fmaf(p2, vx2[j], xv);
          xv = fmaf(p3, vx3[j], xv);
          x[j2 * 4 + j] = xv; s1 += xv; s2 = fmaf(xv, xv, s2);
        }
      }
      s1 = wred(s1); s2 = wred(s2);
      float mu = s1 * (1.f / D);
      float rs = rsqrtf(s2 * (1.f / D) - mu * mu + LN_EPS);
      #pragma unroll
      for (int j2 = 0; j2 < 2; ++j2){
        int c2 = j2 * 256 + lane * 4;
        float4 g  = *(const float4*)(gout + c2);
        float4 bb = *(const float4*)(bout + c2);
        float4 o;
        o.x = (x[j2*4+0] - mu) * rs * g.x + bb.x;
        o.y = (x[j2*4+1] - mu) * rs * g.y + bb.y;
        o.z = (x[j2*4+2] - mu) * rs * g.z + bb.z;
        o.w = (x[j2*4+3] - mu) * rs * g.w + bb.w;
        *(float4*)(out + gbase + (size_t)row * D + c2) = o;
      }
    }
  }
}

extern "C" void kernel_launch(void* const* d_in, const int* in_sizes, int n_in,
                              void* d_out, int out_size, void* d_ws, size_t ws_size,
                              hipStream_t stream){
  const float* hidden = (const float*)d_in[0];
  const void*  mask   = d_in[1];
  const float* slots  = (const float*)d_in[2];
  const float* wq_w   = (const float*)d_in[3];
  const float* wk_w   = (const float*)d_in[4];
  const float* wv_w   = (const float*)d_in[5];
  const float* wq_r   = (const float*)d_in[6];
  const float* wk_r   = (const float*)d_in[7];
  const float* wv_r   = (const float*)d_in[8];
  const float* wo     = (const float*)d_in[9];
  const float* g_ws_  = (const float*)d_in[10];
  const float* b_ws_  = (const float*)d_in[11];
  const float* g_out_ = (const float*)d_in[12];
  const float* b_out_ = (const float*)d_in[13];

  hipLaunchKernelGGL(kprep, dim3(8, 32, 4), dim3(256), 0, stream,
                     wq_w, wk_w, wq_r, wk_r, wo, wv_r, wv_w);
  hipLaunchKernelGGL(kaq,   dim3(4), dim3(512), 0, stream, slots, mask);

  hipLaunchKernelGGL(k4_main, dim3(BTOT / GB), dim3(512), 0, stream,
                     hidden, mask, slots, g_ws_, b_ws_, g_out_, b_out_, (float*)d_out);
}